// Round 1
// baseline (1546.300 us; speedup 1.0000x reference)
//
#include <hip/hip_runtime.h>

// ---------------------------------------------------------------------------
// GCN: 3x GCNConv(9->16->16->16) + MLP(concat 25 ->128->128->1), N=250000,
// E=5,000,000 edges + self loops. f32 in/out; edge_index int32 OR int64
// (detected on device).
// ---------------------------------------------------------------------------

__global__ __launch_bounds__(64) void k_detect(const void* __restrict__ edges,
                                               int* __restrict__ flag, int n_nodes)
{
    if (threadIdx.x == 0 && blockIdx.x == 0) {
        const long long* p = (const long long*)edges;
        int is64 = 1;
        for (int i = 0; i < 16; ++i) {
            long long v = p[i];
            if (v < 0 || v >= (long long)n_nodes) is64 = 0;
        }
        *flag = is64;
    }
}

__global__ __launch_bounds__(256) void k_convert(const void* __restrict__ edges,
                                                 const int* __restrict__ flag,
                                                 int* __restrict__ out, long long total)
{
    long long i = (long long)blockIdx.x * 256 + threadIdx.x;
    if (i >= total) return;
    if (*flag) out[i] = (int)((const long long*)edges)[i];
    else       out[i] = ((const int*)edges)[i];
}

__global__ __launch_bounds__(256) void k_deg_init(float* __restrict__ deg, int n)
{
    int i = blockIdx.x * 256 + threadIdx.x;
    if (i < n) deg[i] = 1.0f;   // self loop contributes 1 to in-degree
}

__global__ __launch_bounds__(256) void k_deg_edges(const int* __restrict__ dst,
                                                   float* __restrict__ deg, long long e)
{
    long long i = (long long)blockIdx.x * 256 + threadIdx.x;
    if (i < e) unsafeAtomicAdd(&deg[dst[i]], 1.0f);
}

__global__ __launch_bounds__(256) void k_dinv(const float* __restrict__ deg,
                                              float* __restrict__ dinv, int n)
{
    int i = blockIdx.x * 256 + threadIdx.x;
    if (i < n) dinv[i] = rsqrtf(deg[i]);   // deg >= 1 always (self loops)
}

// h = x @ W1 (9->16); agg = h * dinv^2  (self-loop term of aggregation)
__global__ __launch_bounds__(256) void k_lin1(const float* __restrict__ x,
                                              const float* __restrict__ W1,
                                              const float* __restrict__ dinv,
                                              float* __restrict__ h,
                                              float* __restrict__ agg, int n)
{
    __shared__ float sW[144];
    if (threadIdx.x < 144) sW[threadIdx.x] = W1[threadIdx.x];
    __syncthreads();
    int i = blockIdx.x * 256 + threadIdx.x;
    if (i >= n) return;
    float xv[9];
#pragma unroll
    for (int k = 0; k < 9; ++k) xv[k] = x[(size_t)i * 9 + k];
    float di = dinv[i];
    float d2 = di * di;
#pragma unroll
    for (int j = 0; j < 16; ++j) {
        float acc = 0.f;
#pragma unroll
        for (int k = 0; k < 9; ++k) acc = fmaf(xv[k], sW[k * 16 + j], acc);
        h[(size_t)i * 16 + j]   = acc;
        agg[(size_t)i * 16 + j] = acc * d2;
    }
}

// t = relu(agg_in + bias); h = t @ W (16->16); agg = h * dinv^2   (in-place on agg)
__global__ __launch_bounds__(256) void k_lin_mid(const float* __restrict__ bias,
                                                 const float* __restrict__ W,
                                                 const float* __restrict__ dinv,
                                                 float* agg,               // read then overwritten (per-thread exclusive)
                                                 float* __restrict__ h, int n)
{
    __shared__ float sW[256];
    __shared__ float sB[16];
    sW[threadIdx.x] = W[threadIdx.x];
    if (threadIdx.x < 16) sB[threadIdx.x] = bias[threadIdx.x];
    __syncthreads();
    int i = blockIdx.x * 256 + threadIdx.x;
    if (i >= n) return;
    float t[16];
#pragma unroll
    for (int k = 0; k < 16; ++k) {
        float v = agg[(size_t)i * 16 + k] + sB[k];
        t[k] = v > 0.f ? v : 0.f;
    }
    float di = dinv[i];
    float d2 = di * di;
#pragma unroll
    for (int j = 0; j < 16; ++j) {
        float acc = 0.f;
#pragma unroll
        for (int k = 0; k < 16; ++k) acc = fmaf(t[k], sW[k * 16 + j], acc);
        h[(size_t)i * 16 + j]   = acc;
        agg[(size_t)i * 16 + j] = acc * d2;
    }
}

// 16 lanes per edge: agg[dst][k] += h[src][k] * dinv[src]*dinv[dst]
__global__ __launch_bounds__(256) void k_scatter(const int* __restrict__ src,
                                                 const int* __restrict__ dst,
                                                 const float* __restrict__ dinv,
                                                 const float* __restrict__ h,
                                                 float* __restrict__ agg, long long e)
{
    long long t = (long long)blockIdx.x * 256 + threadIdx.x;
    long long idx = t >> 4;
    int k = (int)(t & 15);
    if (idx >= e) return;
    int s = src[idx];
    int d = dst[idx];
    float w = dinv[s] * dinv[d];
    float v = h[(size_t)s * 16 + k] * w;
    unsafeAtomicAdd(&agg[(size_t)d * 16 + k], v);
}

// Per node: feat = [x(9), relu(agg3+b3)(16)]; z=relu(feat@Wl2+bl2);
// z2=relu(z@Wl3+bl3); out = z2@Wl4 + bl4.  One wave per node, 64 nodes/block.
__global__ __launch_bounds__(256) void k_mlp(const float* __restrict__ x,
                                             const float* __restrict__ agg3,
                                             const float* __restrict__ b3,
                                             const float* __restrict__ Wl2,
                                             const float* __restrict__ bl2,
                                             const float* __restrict__ Wl3,
                                             const float* __restrict__ bl3,
                                             const float* __restrict__ Wl4,
                                             const float* __restrict__ bl4,
                                             float* __restrict__ out, int n)
{
    __shared__ float sW3[128 * 128];   // 64 KB
    __shared__ float sW4[128];
    __shared__ float sB2[128];
    __shared__ float sB3[128];
    __shared__ float zs[4][128];

    int tid = threadIdx.x;
    for (int i = tid; i < 128 * 128; i += 256) sW3[i] = Wl3[i];
    if (tid < 128) { sW4[tid] = Wl4[tid]; sB2[tid] = bl2[tid]; sB3[tid] = bl3[tid]; }
    __syncthreads();

    int w = tid >> 6;
    int l = tid & 63;
    int base = blockIdx.x * 64 + w * 16;

    for (int it = 0; it < 16; ++it) {
        int node = base + it;
        bool ok = node < n;
        float feat[25];
        if (ok) {
#pragma unroll
            for (int k = 0; k < 9; ++k) feat[k] = x[(size_t)node * 9 + k];
#pragma unroll
            for (int k = 0; k < 16; ++k) {
                float v = agg3[(size_t)node * 16 + k] + b3[k];
                feat[9 + k] = v > 0.f ? v : 0.f;
            }
        } else {
#pragma unroll
            for (int k = 0; k < 25; ++k) feat[k] = 0.f;
        }
        // layer l2: each lane computes hidden units l and l+64
        float a0 = sB2[l], a1 = sB2[l + 64];
#pragma unroll
        for (int k = 0; k < 25; ++k) {
            a0 = fmaf(feat[k], Wl2[k * 128 + l], a0);
            a1 = fmaf(feat[k], Wl2[k * 128 + l + 64], a1);
        }
        a0 = a0 > 0.f ? a0 : 0.f;
        a1 = a1 > 0.f ? a1 : 0.f;
        zs[w][l] = a0;
        zs[w][l + 64] = a1;
        __syncthreads();
        // layer l3
        float c0 = sB3[l], c1 = sB3[l + 64];
        for (int k = 0; k < 128; ++k) {
            float v = zs[w][k];
            c0 = fmaf(v, sW3[k * 128 + l], c0);
            c1 = fmaf(v, sW3[k * 128 + l + 64], c1);
        }
        c0 = c0 > 0.f ? c0 : 0.f;
        c1 = c1 > 0.f ? c1 : 0.f;
        // layer l4: dot with Wl4 across lanes
        float p = c0 * sW4[l] + c1 * sW4[l + 64];
#pragma unroll
        for (int s = 32; s > 0; s >>= 1) p += __shfl_xor(p, s);
        if (ok && l == 0) out[node] = p + bl4[0];
        __syncthreads();
    }
}

extern "C" void kernel_launch(void* const* d_in, const int* in_sizes, int n_in,
                              void* d_out, int out_size, void* d_ws, size_t ws_size,
                              hipStream_t stream)
{
    const float* x   = (const float*)d_in[0];
    const void*  ei  = d_in[1];
    const float* W1  = (const float*)d_in[2];
    const float* b1  = (const float*)d_in[3];
    const float* W2  = (const float*)d_in[4];
    const float* b2  = (const float*)d_in[5];
    const float* W3  = (const float*)d_in[6];
    const float* b3  = (const float*)d_in[7];
    const float* Wl2 = (const float*)d_in[8];
    const float* bl2 = (const float*)d_in[9];
    const float* Wl3 = (const float*)d_in[10];
    const float* bl3 = (const float*)d_in[11];
    const float* Wl4 = (const float*)d_in[12];
    const float* bl4 = (const float*)d_in[13];
    float* out = (float*)d_out;

    int n       = in_sizes[0] / 9;       // 250000
    long long e2 = (long long)in_sizes[1]; // 2*E
    long long E  = e2 / 2;

    char* ws = (char*)d_ws;
    int*   flag    = (int*)ws;
    int*   edges32 = (int*)(ws + 1024);
    float* deg     = (float*)(ws + 1024 + e2 * 4);
    float* dinv    = deg + n;
    float* hbuf    = dinv + n;
    float* agg     = hbuf + (size_t)n * 16;

    const int* src32 = edges32;
    const int* dst32 = edges32 + E;

    int nb_n    = (n + 255) / 256;
    int nb_e    = (int)((E + 255) / 256);
    int nb_e2   = (int)((e2 + 255) / 256);
    int nb_scat = (int)((E * 16 + 255) / 256);

    k_detect<<<1, 64, 0, stream>>>(ei, flag, n);
    k_convert<<<nb_e2, 256, 0, stream>>>(ei, flag, edges32, e2);

    k_deg_init<<<nb_n, 256, 0, stream>>>(deg, n);
    k_deg_edges<<<nb_e, 256, 0, stream>>>(dst32, deg, E);
    k_dinv<<<nb_n, 256, 0, stream>>>(deg, dinv, n);

    // layer 1
    k_lin1<<<nb_n, 256, 0, stream>>>(x, W1, dinv, hbuf, agg, n);
    k_scatter<<<nb_scat, 256, 0, stream>>>(src32, dst32, dinv, hbuf, agg, E);
    // layer 2
    k_lin_mid<<<nb_n, 256, 0, stream>>>(b1, W2, dinv, agg, hbuf, n);
    k_scatter<<<nb_scat, 256, 0, stream>>>(src32, dst32, dinv, hbuf, agg, E);
    // layer 3
    k_lin_mid<<<nb_n, 256, 0, stream>>>(b2, W3, dinv, agg, hbuf, n);
    k_scatter<<<nb_scat, 256, 0, stream>>>(src32, dst32, dinv, hbuf, agg, E);
    // MLP head
    k_mlp<<<(n + 63) / 64, 256, 0, stream>>>(x, agg, b3, Wl2, bl2, Wl3, bl3, Wl4, bl4,
                                             out, n);
}